// Round 12
// baseline (336.592 us; speedup 1.0000x reference)
//
#include <hip/hip_runtime.h>

#define NN 100000
#define NE 3200000
#define DIN 128
#define HD 64
#define DEMB 32
#define NG 256
#define NBUCK ((NN + 255) / 256)        // 391 coarse buckets of 256 dst-nodes
#define NPB 512                         // partition blocks
#define CHUNK ((NE + NPB - 1) / NPB)    // 6250 edges per partition block
#define NM (NBUCK * NPB)                // 200192 histogram-matrix entries
#define NMB ((NM + 1023) / 1024)        // 196 scan blocks
#define GCH 16                          // gather: contiguous nodes per wave-chunk

typedef unsigned short u16;
typedef unsigned int u32;

__device__ __forceinline__ float bflo(u32 u) { return __uint_as_float(u << 16); }
__device__ __forceinline__ float bfhi(u32 u) { return __uint_as_float(u & 0xffff0000u); }
__device__ __forceinline__ u16 f2bf(float f) {          // round-to-nearest-even
    u32 u = __float_as_uint(f);
    return (u16)((u + 0x7fffu + ((u >> 16) & 1u)) >> 16);
}

// ---------------- pass A: per-block coarse histogram (no global atomics) -----
__global__ __launch_bounds__(256) void k_blkhist(const int* __restrict__ dst,
                                                 int* __restrict__ HM, int E) {
    __shared__ int h[NBUCK];
    int blk = blockIdx.x, t = threadIdx.x;
    for (int i = t; i < NBUCK; i += 256) h[i] = 0;
    __syncthreads();
    int beg = blk * CHUNK, end = min(E, beg + CHUNK);
    for (int j = beg + t; j < end; j += 256) atomicAdd(&h[dst[j] >> 8], 1);
    __syncthreads();
    for (int i = t; i < NBUCK; i += 256) HM[i * NPB + blk] = h[i];  // bucket-major
}

// ---------------- scan pass 1: in-place per-1024-block exclusive scan --------
__global__ __launch_bounds__(1024) void k_scanA(int* __restrict__ HM,
                                                int* __restrict__ bsum, int n) {
    __shared__ int s[1024];
    int t = threadIdx.x;
    int idx = blockIdx.x * 1024 + t;
    int v = (idx < n) ? HM[idx] : 0;
    s[t] = v;
    __syncthreads();
    for (int off = 1; off < 1024; off <<= 1) {
        int add = (t >= off) ? s[t - off] : 0;
        __syncthreads();
        s[t] += add;
        __syncthreads();
    }
    if (idx < n) HM[idx] = s[t] - v;            // exclusive within block
    if (t == 1023) bsum[blockIdx.x] = s[t];     // block total
}

// ---------------- scan pass 2: serial scan of block sums ----------------------
__global__ void k_scan2(const int* __restrict__ bsum, int* __restrict__ boff, int nb) {
    if (threadIdx.x == 0 && blockIdx.x == 0) {
        int acc = 0;
        for (int b = 0; b < nb; b++) { boff[b] = acc; acc += bsum[b]; }
        boff[nb] = acc;
    }
}

// ---------------- scan pass 3: add block offsets ------------------------------
__global__ void k_scanC(int* __restrict__ HM, const int* __restrict__ boff, int n) {
    int idx = blockIdx.x * blockDim.x + threadIdx.x;
    if (idx < n) HM[idx] += boff[idx >> 10];
}

// ---------------- pass C: place edges (LDS cursors, deterministic ranges) ----
// part[pos] = src | (dst&255)<<17
__global__ __launch_bounds__(256) void k_place(const int* __restrict__ src,
                                               const int* __restrict__ dst,
                                               const int* __restrict__ HM,
                                               int* __restrict__ part, int E) {
    __shared__ int cur[NBUCK];
    int blk = blockIdx.x, t = threadIdx.x;
    for (int i = t; i < NBUCK; i += 256) cur[i] = HM[i * NPB + blk];
    __syncthreads();
    int beg = blk * CHUNK, end = min(E, beg + CHUNK);
    for (int j = beg + t; j < end; j += 256) {
        int d = dst[j], s = src[j];
        int pos = atomicAdd(&cur[d >> 8], 1);   // LDS atomic — no global contention
        part[pos] = s | ((d & 255) << 17);
    }
}

// ---------------- phase B: per-bucket fine sort + degree + rowptr + dinv -----
__global__ __launch_bounds__(256) void k_phaseB(const int* __restrict__ part,
                                                const int* __restrict__ HM,
                                                int* __restrict__ rowptr,
                                                int* __restrict__ ssrc,
                                                float* __restrict__ dinv, int E) {
    __shared__ int cnt[256];
    __shared__ int sc[256];
    int b = blockIdx.x;
    int t = threadIdx.x;
    int beg = HM[b * NPB];
    int end = (b == NBUCK - 1) ? E : HM[(b + 1) * NPB];
    int node0 = b << 8;
    int nnode = NN - node0 < 256 ? NN - node0 : 256;
    cnt[t] = 0;
    __syncthreads();
    for (int j = beg + t; j < end; j += 256) atomicAdd(&cnt[part[j] >> 17], 1);
    __syncthreads();
    int v = cnt[t];
    sc[t] = v;
    __syncthreads();
    for (int off = 1; off < 256; off <<= 1) {
        int add = (t >= off) ? sc[t - off] : 0;
        __syncthreads();
        sc[t] += add;
        __syncthreads();
    }
    int excl = sc[t] - v;
    if (t < nnode) {
        rowptr[node0 + t] = beg + excl;
        dinv[node0 + t] = rsqrtf((float)v + 1.0f);
    }
    if (b == NBUCK - 1 && t == 0) rowptr[NN] = E;
    __syncthreads();
    cnt[t] = beg + excl;    // reuse as cursor
    __syncthreads();
    for (int j = beg + t; j < end; j += 256) {
        int e = part[j];
        int pos = atomicAdd(&cnt[e >> 17], 1);
        ssrc[pos] = e & 0x1FFFF;
    }
}

// ---------------- GEMM: U[n][64] = bf16((X[n][K] @ W[K][64]) * dinv[row]) ----
// 64x64 tile per block, 256 threads, 4x4 register tile (named float4s).
// __launch_bounds__(256,4) caps VGPRs ~128 -> no spill (R9 lesson).
template <int K>
__global__ __launch_bounds__(256, 4) void k_gemm(const float* __restrict__ X,
                                                 const float* __restrict__ W,
                                                 const float* __restrict__ dinv,
                                                 u16* __restrict__ U, int n) {
    __shared__ __align__(16) float xt[32][68];   // transposed X chunk, pad->stride 68
    __shared__ __align__(16) float wlc[32][64];  // W chunk
    int tid = threadIdx.x;
    int cg = tid & 15;        // col group: cols 4*cg..4*cg+3
    int rs = tid >> 4;        // row group: rows 4*rs..4*rs+3
    int row0 = blockIdx.x * 64;
    float4 acc0 = {0.f, 0.f, 0.f, 0.f};
    float4 acc1 = {0.f, 0.f, 0.f, 0.f};
    float4 acc2 = {0.f, 0.f, 0.f, 0.f};
    float4 acc3 = {0.f, 0.f, 0.f, 0.f};
    for (int kc = 0; kc < K; kc += 32) {        // runtime loop: keep live ranges short
        __syncthreads();
        for (int p = 0; p < 2; ++p) {
            int idx = tid + p * 256;
            int r = idx >> 3;            // 0..63
            int c4 = idx & 7;            // 0..7
            int row = row0 + r;
            float4 v = {0.f, 0.f, 0.f, 0.f};
            if (row < n) v = *reinterpret_cast<const float4*>(&X[(size_t)row * K + kc + c4 * 4]);
            xt[c4 * 4 + 0][r] = v.x;
            xt[c4 * 4 + 1][r] = v.y;
            xt[c4 * 4 + 2][r] = v.z;
            xt[c4 * 4 + 3][r] = v.w;
        }
        for (int p = 0; p < 2; ++p) {
            int idx = tid + p * 256;     // float4 index, 512 total
            int kr = idx >> 4;           // 0..31
            int c4 = idx & 15;           // 0..15
            *reinterpret_cast<float4*>(&wlc[kr][c4 * 4]) =
                *reinterpret_cast<const float4*>(&W[(size_t)(kc + kr) * 64 + c4 * 4]);
        }
        __syncthreads();
#pragma unroll
        for (int k = 0; k < 32; ++k) {
            float4 xv = *reinterpret_cast<const float4*>(&xt[k][rs * 4]);
            float4 wv = *reinterpret_cast<const float4*>(&wlc[k][cg * 4]);
            acc0.x += xv.x * wv.x; acc0.y += xv.x * wv.y; acc0.z += xv.x * wv.z; acc0.w += xv.x * wv.w;
            acc1.x += xv.y * wv.x; acc1.y += xv.y * wv.y; acc1.z += xv.y * wv.z; acc1.w += xv.y * wv.w;
            acc2.x += xv.z * wv.x; acc2.y += xv.z * wv.y; acc2.z += xv.z * wv.z; acc2.w += xv.z * wv.w;
            acc3.x += xv.w * wv.x; acc3.y += xv.w * wv.y; acc3.z += xv.w * wv.z; acc3.w += xv.w * wv.w;
        }
    }
    int rbase = row0 + rs * 4;
    float dv;
    if (rbase + 0 < n) { dv = dinv[rbase + 0];
        ushort4 o = {f2bf(acc0.x * dv), f2bf(acc0.y * dv), f2bf(acc0.z * dv), f2bf(acc0.w * dv)};
        *reinterpret_cast<ushort4*>(&U[(size_t)(rbase + 0) * 64 + cg * 4]) = o; }
    if (rbase + 1 < n) { dv = dinv[rbase + 1];
        ushort4 o = {f2bf(acc1.x * dv), f2bf(acc1.y * dv), f2bf(acc1.z * dv), f2bf(acc1.w * dv)};
        *reinterpret_cast<ushort4*>(&U[(size_t)(rbase + 1) * 64 + cg * 4]) = o; }
    if (rbase + 2 < n) { dv = dinv[rbase + 2];
        ushort4 o = {f2bf(acc2.x * dv), f2bf(acc2.y * dv), f2bf(acc2.z * dv), f2bf(acc2.w * dv)};
        *reinterpret_cast<ushort4*>(&U[(size_t)(rbase + 2) * 64 + cg * 4]) = o; }
    if (rbase + 3 < n) { dv = dinv[rbase + 3];
        ushort4 o = {f2bf(acc3.x * dv), f2bf(acc3.y * dv), f2bf(acc3.z * dv), f2bf(acc3.w * dv)};
        *reinterpret_cast<ushort4*>(&U[(size_t)(rbase + 3) * 64 + cg * 4]) = o; }
}

// ---------------- gather-reduce per dst node (bf16 U rows) --------------------
// h[d] = relu(dinv[d] * (sum_{s in N(d)} U[s] + U[d]) + b)
// lane mapping: g = lane&7 (edge slot), c = lane>>3 (16B chunk = 8 bf16 ch).
// 8 edges per wave-load instruction; up to 32 edges (4 loads) in flight.
// Contiguous GCH-node chunk per wave. FUSE_POOL: register-accumulate h while
// batch id (sorted, wave-uniform) constant; flush = 64 distinct-addr atomics.
#define ACC8(u, L, H) \
    L.x += bflo(u.x); L.y += bfhi(u.x); L.z += bflo(u.y); L.w += bfhi(u.y); \
    H.x += bflo(u.z); H.y += bfhi(u.z); H.z += bflo(u.w); H.w += bfhi(u.w);

template <bool FUSE_POOL>
__global__ void k_gather(const int* __restrict__ rowptr, const int* __restrict__ ssrc,
                         const float* __restrict__ dinv, const u16* __restrict__ U,
                         const float* __restrict__ bias, const int* __restrict__ batch,
                         float* __restrict__ outbuf, int n) {
    int gtid = blockIdx.x * blockDim.x + threadIdx.x;
    int lane = gtid & 63;
    int g = lane & 7;        // edge slot
    int c = lane >> 3;       // 16B chunk within the 128B row (0..7)
    int w = gtid >> 6;
    int nw = (gridDim.x * blockDim.x) >> 6;
    float bv = bias[lane];
    int nch = (n + GCH - 1) / GCH;
    for (int ch = w; ch < nch; ch += nw) {
        int d0 = ch * GCH, d1 = min(n, d0 + GCH);
        float pacc = 0.f;
        int curg = FUSE_POOL ? batch[d0] : 0;
        for (int d = d0; d < d1; ++d) {
            int beg = rowptr[d], end = rowptr[d + 1];
            float4 aL0 = {0.f,0.f,0.f,0.f}, aH0 = {0.f,0.f,0.f,0.f};
            float4 aL1 = {0.f,0.f,0.f,0.f}, aH1 = {0.f,0.f,0.f,0.f};
            float4 aL2 = {0.f,0.f,0.f,0.f}, aH2 = {0.f,0.f,0.f,0.f};
            float4 aL3 = {0.f,0.f,0.f,0.f}, aH3 = {0.f,0.f,0.f,0.f};
            int j = beg;
            for (; j + 32 <= end; j += 32) {
                int s0 = ssrc[j + g];
                int s1 = ssrc[j + 8 + g];
                int s2 = ssrc[j + 16 + g];
                int s3 = ssrc[j + 24 + g];
                uint4 u0 = *reinterpret_cast<const uint4*>(&U[(size_t)s0 * 64 + c * 8]);
                uint4 u1 = *reinterpret_cast<const uint4*>(&U[(size_t)s1 * 64 + c * 8]);
                uint4 u2 = *reinterpret_cast<const uint4*>(&U[(size_t)s2 * 64 + c * 8]);
                uint4 u3 = *reinterpret_cast<const uint4*>(&U[(size_t)s3 * 64 + c * 8]);
                ACC8(u0, aL0, aH0); ACC8(u1, aL1, aH1);
                ACC8(u2, aL2, aH2); ACC8(u3, aL3, aH3);
            }
            if (j + 16 <= end) {
                int s0 = ssrc[j + g];
                int s1 = ssrc[j + 8 + g];
                uint4 u0 = *reinterpret_cast<const uint4*>(&U[(size_t)s0 * 64 + c * 8]);
                uint4 u1 = *reinterpret_cast<const uint4*>(&U[(size_t)s1 * 64 + c * 8]);
                ACC8(u0, aL0, aH0); ACC8(u1, aL1, aH1);
                j += 16;
            }
            if (j + 8 <= end) {
                int s2 = ssrc[j + g];
                uint4 u2 = *reinterpret_cast<const uint4*>(&U[(size_t)s2 * 64 + c * 8]);
                ACC8(u2, aL2, aH2);
                j += 8;
            }
            if (j + g < end) {
                int s3 = ssrc[j + g];
                uint4 u3 = *reinterpret_cast<const uint4*>(&U[(size_t)s3 * 64 + c * 8]);
                ACC8(u3, aL3, aH3);
            }
            float4 aL, aH;
            aL.x = (aL0.x + aL1.x) + (aL2.x + aL3.x);
            aL.y = (aL0.y + aL1.y) + (aL2.y + aL3.y);
            aL.z = (aL0.z + aL1.z) + (aL2.z + aL3.z);
            aL.w = (aL0.w + aL1.w) + (aL2.w + aL3.w);
            aH.x = (aH0.x + aH1.x) + (aH2.x + aH3.x);
            aH.y = (aH0.y + aH1.y) + (aH2.y + aH3.y);
            aH.z = (aH0.z + aH1.z) + (aH2.z + aH3.z);
            aH.w = (aH0.w + aH1.w) + (aH2.w + aH3.w);
            // reduce over the 8 edge slots (xor 1,2,4)
#pragma unroll
            for (int m = 1; m <= 4; m <<= 1) {
                aL.x += __shfl_xor(aL.x, m); aL.y += __shfl_xor(aL.y, m);
                aL.z += __shfl_xor(aL.z, m); aL.w += __shfl_xor(aL.w, m);
                aH.x += __shfl_xor(aH.x, m); aH.y += __shfl_xor(aH.y, m);
                aH.z += __shfl_xor(aH.z, m); aH.w += __shfl_xor(aH.w, m);
            }
            // channel = c*8 + g = lane; pick component g from the 8 floats
            float4 q = (g & 4) ? aH : aL;
            float hv = (g & 2) ? ((g & 1) ? q.w : q.z) : ((g & 1) ? q.y : q.x);
            float ud = __uint_as_float(((u32)U[(size_t)d * 64 + lane]) << 16);
            float dd = dinv[d];
            float h = (hv + ud) * dd + bv;
            h = h > 0.f ? h : 0.f;
            if (FUSE_POOL) {
                int gb = batch[d];
                if (gb != curg) {
                    atomicAdd(&outbuf[(size_t)curg * 64 + lane], pacc);
                    pacc = 0.f;
                    curg = gb;
                }
                pacc += h;
            } else {
                outbuf[(size_t)d * 64 + lane] = h;     // coalesced 256B wave store
            }
        }
        if (FUSE_POOL) atomicAdd(&outbuf[(size_t)curg * 64 + lane], pacc);
    }
}

// ---------------- head: out[g] = (sums[g]/cnt[g]) @ Wl + bl ------------------
// cnt[g] from binary search over sorted batch (no contended atomics).
__global__ void k_final(const float* __restrict__ sums, const int* __restrict__ batch,
                        const float* __restrict__ Wl, const float* __restrict__ bl,
                        float* __restrict__ out, int n) {
    __shared__ float pooled[64];
    int g = blockIdx.x;
    int t = threadIdx.x;
    int lo = 0, hi = n;
    while (lo < hi) { int m = (lo + hi) >> 1; if (batch[m] < g) lo = m + 1; else hi = m; }
    int lo2 = lo, hi2 = n;
    while (lo2 < hi2) { int m = (lo2 + hi2) >> 1; if (batch[m] < g + 1) lo2 = m + 1; else hi2 = m; }
    float c = (float)(lo2 - lo);
    c = c < 1.0f ? 1.0f : c;
    pooled[t] = sums[g * 64 + t] / c;
    __syncthreads();
    if (t < 32) {
        float acc = bl[t];
#pragma unroll 8
        for (int k = 0; k < 64; k++) acc += pooled[k] * Wl[k * 32 + t];
        out[g * 32 + t] = acc;
    }
}

extern "C" void kernel_launch(void* const* d_in, const int* in_sizes, int n_in,
                              void* d_out, int out_size, void* d_ws, size_t ws_size,
                              hipStream_t stream) {
    const float* x = (const float*)d_in[0];
    const int* ei = (const int*)d_in[1];      // [2, E] int32
    const int* batch = (const int*)d_in[2];   // [N] int32
    const float* W1 = (const float*)d_in[4];
    const float* b1 = (const float*)d_in[5];
    const float* W2 = (const float*)d_in[6];
    const float* b2 = (const float*)d_in[7];
    const float* Wl = (const float*)d_in[8];
    const float* bl = (const float*)d_in[9];
    float* out = (float*)d_out;

    const int* esrc = ei;
    const int* edst = ei + NE;

    char* ws = (char*)d_ws;
    size_t off = 0;
    auto alloc = [&](size_t bytes) {
        void* p = ws + off;
        off += (bytes + 255) & ~size_t(255);
        return p;
    };
    float* dinv   = (float*)alloc((size_t)NN * 4);
    int*   rowptr = (int*)alloc((size_t)(NN + 1) * 4);
    int*   HM     = (int*)alloc((size_t)NM * 4);        // 0.8 MB scan matrix
    int*   bsum   = (int*)alloc((size_t)(NMB + 1) * 4);
    int*   boff   = (int*)alloc((size_t)(NMB + 1) * 4);
    int*   ssrc   = (int*)alloc((size_t)NE * 4);        // 12.8 MB
    u16*   tbuf   = (u16*)alloc((size_t)NE * 4);        // 12.8 MB: part(int) overlay / U(bf16)
    float* agg    = (float*)alloc((size_t)NN * HD * 4); // 25.6 MB (h1)
    float* sums   = (float*)alloc((size_t)NG * HD * 4);
    // part overlays tbuf: dead before gemm1 writes tbuf
    int* part = (int*)tbuf;

    // 1. contention-free radix partition -> ssrc (+ rowptr, dinv)
    k_blkhist<<<NPB, 256, 0, stream>>>(edst, HM, NE);
    k_scanA<<<NMB, 1024, 0, stream>>>(HM, bsum, NM);
    k_scan2<<<1, 64, 0, stream>>>(bsum, boff, NMB);
    k_scanC<<<(NM + 255) / 256, 256, 0, stream>>>(HM, boff, NM);
    k_place<<<NPB, 256, 0, stream>>>(esrc, edst, HM, part, NE);
    k_phaseB<<<NBUCK, 256, 0, stream>>>(part, HM, rowptr, ssrc, dinv, NE);

    // 2. layer 1: U1 = bf16((x@W1)*dinv) ; h1 = relu(dinv*(gather+self) + b1) -> agg
    k_gemm<DIN><<<(NN + 63) / 64, 256, 0, stream>>>(x, W1, dinv, tbuf, NN);
    k_gather<false><<<2048, 256, 0, stream>>>(rowptr, ssrc, dinv, tbuf, b1, batch, agg, NN);

    // 3. layer 2: U2 = bf16((h1@W2)*dinv) ; h2 fused straight into pool sums
    k_gemm<HD><<<(NN + 63) / 64, 256, 0, stream>>>(agg, W2, dinv, tbuf, NN);
    hipMemsetAsync(sums, 0, (size_t)NG * HD * 4, stream);
    k_gather<true><<<2048, 256, 0, stream>>>(rowptr, ssrc, dinv, tbuf, b2, batch, sums, NN);

    // 4. head (binary-search counts)
    k_final<<<NG, 64, 0, stream>>>(sums, batch, Wl, bl, out, NN);
}

// Round 13
// 280.047 us; speedup vs baseline: 1.2019x; 1.2019x over previous
//
#include <hip/hip_runtime.h>

#define NN 100000
#define NE 3200000
#define DIN 128
#define HD 64
#define DEMB 32
#define NG 256
#define NBUCK ((NN + 255) / 256)        // 391 coarse buckets of 256 dst-nodes
#define NPB 512                         // partition blocks
#define CHUNK ((NE + NPB - 1) / NPB)    // 6250 edges per partition block
#define NM (NBUCK * NPB)                // 200192 histogram-matrix entries
#define NMB ((NM + 1023) / 1024)        // 196 scan blocks

typedef unsigned short u16;
typedef unsigned int u32;

__device__ __forceinline__ float bflo(u32 u) { return __uint_as_float(u << 16); }
__device__ __forceinline__ float bfhi(u32 u) { return __uint_as_float(u & 0xffff0000u); }
__device__ __forceinline__ u16 f2bf(float f) {          // round-to-nearest-even
    u32 u = __float_as_uint(f);
    return (u16)((u + 0x7fffu + ((u >> 16) & 1u)) >> 16);
}

// ---------------- pass A: per-block coarse histogram (no global atomics) -----
__global__ __launch_bounds__(256) void k_blkhist(const int* __restrict__ dst,
                                                 int* __restrict__ HM, int E) {
    __shared__ int h[NBUCK];
    int blk = blockIdx.x, t = threadIdx.x;
    for (int i = t; i < NBUCK; i += 256) h[i] = 0;
    __syncthreads();
    int beg = blk * CHUNK, end = min(E, beg + CHUNK);
    for (int j = beg + t; j < end; j += 256) atomicAdd(&h[dst[j] >> 8], 1);
    __syncthreads();
    for (int i = t; i < NBUCK; i += 256) HM[i * NPB + blk] = h[i];  // bucket-major
}

// ---------------- scan pass 1: in-place per-1024-block exclusive scan --------
__global__ __launch_bounds__(1024) void k_scanA(int* __restrict__ HM,
                                                int* __restrict__ bsum, int n) {
    __shared__ int s[1024];
    int t = threadIdx.x;
    int idx = blockIdx.x * 1024 + t;
    int v = (idx < n) ? HM[idx] : 0;
    s[t] = v;
    __syncthreads();
    for (int off = 1; off < 1024; off <<= 1) {
        int add = (t >= off) ? s[t - off] : 0;
        __syncthreads();
        s[t] += add;
        __syncthreads();
    }
    if (idx < n) HM[idx] = s[t] - v;            // exclusive within block
    if (t == 1023) bsum[blockIdx.x] = s[t];     // block total
}

// ---------------- scan pass 2: parallel scan of block sums (nb <= 256) -------
__global__ __launch_bounds__(256) void k_scan2(const int* __restrict__ bsum,
                                               int* __restrict__ boff, int nb) {
    __shared__ int s[256];
    int t = threadIdx.x;
    int v = (t < nb) ? bsum[t] : 0;
    s[t] = v;
    __syncthreads();
    for (int off = 1; off < 256; off <<= 1) {
        int add = (t >= off) ? s[t - off] : 0;
        __syncthreads();
        s[t] += add;
        __syncthreads();
    }
    if (t < nb) boff[t] = s[t] - v;
    if (t == nb - 1) boff[nb] = s[t];
}

// ---------------- scan pass 3: add block offsets ------------------------------
__global__ void k_scanC(int* __restrict__ HM, const int* __restrict__ boff, int n) {
    int idx = blockIdx.x * blockDim.x + threadIdx.x;
    if (idx < n) HM[idx] += boff[idx >> 10];
}

// ---------------- pass C: place edges (LDS cursors, deterministic ranges) ----
// part[pos] = src | (dst&255)<<17
__global__ __launch_bounds__(256) void k_place(const int* __restrict__ src,
                                               const int* __restrict__ dst,
                                               const int* __restrict__ HM,
                                               int* __restrict__ part, int E) {
    __shared__ int cur[NBUCK];
    int blk = blockIdx.x, t = threadIdx.x;
    for (int i = t; i < NBUCK; i += 256) cur[i] = HM[i * NPB + blk];
    __syncthreads();
    int beg = blk * CHUNK, end = min(E, beg + CHUNK);
    for (int j = beg + t; j < end; j += 256) {
        int d = dst[j], s = src[j];
        int pos = atomicAdd(&cur[d >> 8], 1);   // LDS atomic — no global contention
        part[pos] = s | ((d & 255) << 17);
    }
}

// ---------------- phase B: per-bucket fine sort + degree + rowptr + dinv -----
__global__ __launch_bounds__(256) void k_phaseB(const int* __restrict__ part,
                                                const int* __restrict__ HM,
                                                int* __restrict__ rowptr,
                                                int* __restrict__ ssrc,
                                                float* __restrict__ dinv, int E) {
    __shared__ int cnt[256];
    __shared__ int sc[256];
    int b = blockIdx.x;
    int t = threadIdx.x;
    int beg = HM[b * NPB];
    int end = (b == NBUCK - 1) ? E : HM[(b + 1) * NPB];
    int node0 = b << 8;
    int nnode = NN - node0 < 256 ? NN - node0 : 256;
    cnt[t] = 0;
    __syncthreads();
    for (int j = beg + t; j < end; j += 256) atomicAdd(&cnt[part[j] >> 17], 1);
    __syncthreads();
    int v = cnt[t];
    sc[t] = v;
    __syncthreads();
    for (int off = 1; off < 256; off <<= 1) {
        int add = (t >= off) ? sc[t - off] : 0;
        __syncthreads();
        sc[t] += add;
        __syncthreads();
    }
    int excl = sc[t] - v;
    if (t < nnode) {
        rowptr[node0 + t] = beg + excl;
        dinv[node0 + t] = rsqrtf((float)v + 1.0f);
    }
    if (b == NBUCK - 1 && t == 0) rowptr[NN] = E;
    __syncthreads();
    cnt[t] = beg + excl;    // reuse as cursor
    __syncthreads();
    for (int j = beg + t; j < end; j += 256) {
        int e = part[j];
        int pos = atomicAdd(&cnt[e >> 17], 1);
        ssrc[pos] = e & 0x1FFFF;
    }
}

// ---------------- GEMM: U[n][64] = bf16((X[n][K] @ W[K][64]) * dinv[row]) ----
// XT = float (layer 1) or u16/bf16 (layer 2). 64x64 tile, 256 threads,
// 4x4 register tile (named float4s). __launch_bounds__(256,4) -> no spill.
template <int K, typename XT>
__global__ __launch_bounds__(256, 4) void k_gemm(const XT* __restrict__ X,
                                                 const float* __restrict__ W,
                                                 const float* __restrict__ dinv,
                                                 u16* __restrict__ U, int n) {
    __shared__ __align__(16) float xt[32][68];   // transposed X chunk, pad->stride 68
    __shared__ __align__(16) float wlc[32][64];  // W chunk
    int tid = threadIdx.x;
    int cg = tid & 15;        // col group: cols 4*cg..4*cg+3
    int rs = tid >> 4;        // row group: rows 4*rs..4*rs+3
    int row0 = blockIdx.x * 64;
    float4 acc0 = {0.f, 0.f, 0.f, 0.f};
    float4 acc1 = {0.f, 0.f, 0.f, 0.f};
    float4 acc2 = {0.f, 0.f, 0.f, 0.f};
    float4 acc3 = {0.f, 0.f, 0.f, 0.f};
    for (int kc = 0; kc < K; kc += 32) {        // runtime loop: keep live ranges short
        __syncthreads();
        for (int p = 0; p < 2; ++p) {
            int idx = tid + p * 256;
            int r = idx >> 3;            // 0..63
            int c4 = idx & 7;            // 0..7
            int row = row0 + r;
            float4 v = {0.f, 0.f, 0.f, 0.f};
            if (row < n) {
                if constexpr (sizeof(XT) == 4) {
                    v = *reinterpret_cast<const float4*>(&X[(size_t)row * K + kc + c4 * 4]);
                } else {
                    ushort4 b = *reinterpret_cast<const ushort4*>(&X[(size_t)row * K + kc + c4 * 4]);
                    v.x = __uint_as_float((u32)b.x << 16);
                    v.y = __uint_as_float((u32)b.y << 16);
                    v.z = __uint_as_float((u32)b.z << 16);
                    v.w = __uint_as_float((u32)b.w << 16);
                }
            }
            xt[c4 * 4 + 0][r] = v.x;
            xt[c4 * 4 + 1][r] = v.y;
            xt[c4 * 4 + 2][r] = v.z;
            xt[c4 * 4 + 3][r] = v.w;
        }
        for (int p = 0; p < 2; ++p) {
            int idx = tid + p * 256;     // float4 index, 512 total
            int kr = idx >> 4;           // 0..31
            int c4 = idx & 15;           // 0..15
            *reinterpret_cast<float4*>(&wlc[kr][c4 * 4]) =
                *reinterpret_cast<const float4*>(&W[(size_t)(kc + kr) * 64 + c4 * 4]);
        }
        __syncthreads();
#pragma unroll
        for (int k = 0; k < 32; ++k) {
            float4 xv = *reinterpret_cast<const float4*>(&xt[k][rs * 4]);
            float4 wv = *reinterpret_cast<const float4*>(&wlc[k][cg * 4]);
            acc0.x += xv.x * wv.x; acc0.y += xv.x * wv.y; acc0.z += xv.x * wv.z; acc0.w += xv.x * wv.w;
            acc1.x += xv.y * wv.x; acc1.y += xv.y * wv.y; acc1.z += xv.y * wv.z; acc1.w += xv.y * wv.w;
            acc2.x += xv.z * wv.x; acc2.y += xv.z * wv.y; acc2.z += xv.z * wv.z; acc2.w += xv.z * wv.w;
            acc3.x += xv.w * wv.x; acc3.y += xv.w * wv.y; acc3.z += xv.w * wv.z; acc3.w += xv.w * wv.w;
        }
    }
    int rbase = row0 + rs * 4;
    float dv;
    if (rbase + 0 < n) { dv = dinv[rbase + 0];
        ushort4 o = {f2bf(acc0.x * dv), f2bf(acc0.y * dv), f2bf(acc0.z * dv), f2bf(acc0.w * dv)};
        *reinterpret_cast<ushort4*>(&U[(size_t)(rbase + 0) * 64 + cg * 4]) = o; }
    if (rbase + 1 < n) { dv = dinv[rbase + 1];
        ushort4 o = {f2bf(acc1.x * dv), f2bf(acc1.y * dv), f2bf(acc1.z * dv), f2bf(acc1.w * dv)};
        *reinterpret_cast<ushort4*>(&U[(size_t)(rbase + 1) * 64 + cg * 4]) = o; }
    if (rbase + 2 < n) { dv = dinv[rbase + 2];
        ushort4 o = {f2bf(acc2.x * dv), f2bf(acc2.y * dv), f2bf(acc2.z * dv), f2bf(acc2.w * dv)};
        *reinterpret_cast<ushort4*>(&U[(size_t)(rbase + 2) * 64 + cg * 4]) = o; }
    if (rbase + 3 < n) { dv = dinv[rbase + 3];
        ushort4 o = {f2bf(acc3.x * dv), f2bf(acc3.y * dv), f2bf(acc3.z * dv), f2bf(acc3.w * dv)};
        *reinterpret_cast<ushort4*>(&U[(size_t)(rbase + 3) * 64 + cg * 4]) = o; }
}

// ---------------- gather-reduce per dst node (bf16 U rows, bf16 h out) --------
// h[d] = relu(dinv[d] * (sum_{s in N(d)} U[s] + U[d]) + b)
// R11 structure (proven): g = lane&7 edge slot, c = lane>>3 16B chunk;
// 8 edges per wave-load, 16 edges (2 loads) in flight; grid-stride per node.
// R12 lesson: 32-deep unroll doubled VGPR, halved occupancy, +60% time. Keep 16.
__global__ void k_gather(const int* __restrict__ rowptr, const int* __restrict__ ssrc,
                         const float* __restrict__ dinv, const u16* __restrict__ U,
                         const float* __restrict__ bias,
                         u16* __restrict__ outbuf, int n) {
    int gtid = blockIdx.x * blockDim.x + threadIdx.x;
    int lane = gtid & 63;
    int g = lane & 7;        // edge slot
    int c = lane >> 3;       // 16B chunk within the 128B row (0..7)
    int w = gtid >> 6;
    int nw = (gridDim.x * blockDim.x) >> 6;
    float bv = bias[lane];
    for (int d = w; d < n; d += nw) {
        int beg = rowptr[d], end = rowptr[d + 1];
        float4 aL0 = {0.f,0.f,0.f,0.f}, aH0 = {0.f,0.f,0.f,0.f};
        float4 aL1 = {0.f,0.f,0.f,0.f}, aH1 = {0.f,0.f,0.f,0.f};
        int j = beg;
        for (; j + 16 <= end; j += 16) {
            int s0 = ssrc[j + g];
            int s1 = ssrc[j + 8 + g];
            uint4 u0 = *reinterpret_cast<const uint4*>(&U[(size_t)s0 * 64 + c * 8]);
            uint4 u1 = *reinterpret_cast<const uint4*>(&U[(size_t)s1 * 64 + c * 8]);
            aL0.x += bflo(u0.x); aL0.y += bfhi(u0.x); aL0.z += bflo(u0.y); aL0.w += bfhi(u0.y);
            aH0.x += bflo(u0.z); aH0.y += bfhi(u0.z); aH0.z += bflo(u0.w); aH0.w += bfhi(u0.w);
            aL1.x += bflo(u1.x); aL1.y += bfhi(u1.x); aL1.z += bflo(u1.y); aL1.w += bfhi(u1.y);
            aH1.x += bflo(u1.z); aH1.y += bfhi(u1.z); aH1.z += bflo(u1.w); aH1.w += bfhi(u1.w);
        }
        if (j + 8 <= end) {
            int s0 = ssrc[j + g];
            uint4 u0 = *reinterpret_cast<const uint4*>(&U[(size_t)s0 * 64 + c * 8]);
            aL0.x += bflo(u0.x); aL0.y += bfhi(u0.x); aL0.z += bflo(u0.y); aL0.w += bfhi(u0.y);
            aH0.x += bflo(u0.z); aH0.y += bfhi(u0.z); aH0.z += bflo(u0.w); aH0.w += bfhi(u0.w);
            j += 8;
        }
        if (j + g < end) {
            int s1 = ssrc[j + g];
            uint4 u1 = *reinterpret_cast<const uint4*>(&U[(size_t)s1 * 64 + c * 8]);
            aL1.x += bflo(u1.x); aL1.y += bfhi(u1.x); aL1.z += bflo(u1.y); aL1.w += bfhi(u1.y);
            aH1.x += bflo(u1.z); aH1.y += bfhi(u1.z); aH1.z += bflo(u1.w); aH1.w += bfhi(u1.w);
        }
        aL0.x += aL1.x; aL0.y += aL1.y; aL0.z += aL1.z; aL0.w += aL1.w;
        aH0.x += aH1.x; aH0.y += aH1.y; aH0.z += aH1.z; aH0.w += aH1.w;
        // reduce over the 8 edge slots (xor 1,2,4)
#pragma unroll
        for (int m = 1; m <= 4; m <<= 1) {
            aL0.x += __shfl_xor(aL0.x, m); aL0.y += __shfl_xor(aL0.y, m);
            aL0.z += __shfl_xor(aL0.z, m); aL0.w += __shfl_xor(aL0.w, m);
            aH0.x += __shfl_xor(aH0.x, m); aH0.y += __shfl_xor(aH0.y, m);
            aH0.z += __shfl_xor(aH0.z, m); aH0.w += __shfl_xor(aH0.w, m);
        }
        // channel = c*8 + g = lane; pick component g from the 8 floats
        float4 q = (g & 4) ? aH0 : aL0;
        float hv = (g & 2) ? ((g & 1) ? q.w : q.z) : ((g & 1) ? q.y : q.x);
        float ud = __uint_as_float(((u32)U[(size_t)d * 64 + lane]) << 16);
        float dd = dinv[d];
        float h = (hv + ud) * dd + bv;
        h = h > 0.f ? h : 0.f;
        outbuf[(size_t)d * 64 + lane] = f2bf(h);   // coalesced 128B wave store
    }
}

// ---------------- pool: segmented sum over sorted batch (bf16 h) --------------
__global__ __launch_bounds__(256) void k_pool(const u16* __restrict__ h,
                                              const int* __restrict__ batch,
                                              float* __restrict__ sums, int n) {
    int tid = blockIdx.x * blockDim.x + threadIdx.x;
    int wave = tid >> 6;
    int lane = tid & 63;
    int node0 = wave * 64;
    if (node0 >= n) return;
    int nodeEnd = min(n, node0 + 64);
    float acc = 0.f;
    int curg = batch[node0];
    for (int nd = node0; nd < nodeEnd; ++nd) {
        int g = batch[nd];
        if (g != curg) {
            atomicAdd(&sums[(size_t)curg * 64 + lane], acc);
            acc = 0.f;
            curg = g;
        }
        acc += __uint_as_float(((u32)h[(size_t)nd * 64 + lane]) << 16);
    }
    atomicAdd(&sums[(size_t)curg * 64 + lane], acc);
}

// ---------------- head: out[g] = (sums[g]/cnt[g]) @ Wl + bl ------------------
// cnt[g] from binary search over sorted batch (no contended atomics).
__global__ void k_final(const float* __restrict__ sums, const int* __restrict__ batch,
                        const float* __restrict__ Wl, const float* __restrict__ bl,
                        float* __restrict__ out, int n) {
    __shared__ float pooled[64];
    int g = blockIdx.x;
    int t = threadIdx.x;
    int lo = 0, hi = n;
    while (lo < hi) { int m = (lo + hi) >> 1; if (batch[m] < g) lo = m + 1; else hi = m; }
    int lo2 = lo, hi2 = n;
    while (lo2 < hi2) { int m = (lo2 + hi2) >> 1; if (batch[m] < g + 1) lo2 = m + 1; else hi2 = m; }
    float c = (float)(lo2 - lo);
    c = c < 1.0f ? 1.0f : c;
    pooled[t] = sums[g * 64 + t] / c;
    __syncthreads();
    if (t < 32) {
        float acc = bl[t];
#pragma unroll 8
        for (int k = 0; k < 64; k++) acc += pooled[k] * Wl[k * 32 + t];
        out[g * 32 + t] = acc;
    }
}

extern "C" void kernel_launch(void* const* d_in, const int* in_sizes, int n_in,
                              void* d_out, int out_size, void* d_ws, size_t ws_size,
                              hipStream_t stream) {
    const float* x = (const float*)d_in[0];
    const int* ei = (const int*)d_in[1];      // [2, E] int32
    const int* batch = (const int*)d_in[2];   // [N] int32
    const float* W1 = (const float*)d_in[4];
    const float* b1 = (const float*)d_in[5];
    const float* W2 = (const float*)d_in[6];
    const float* b2 = (const float*)d_in[7];
    const float* Wl = (const float*)d_in[8];
    const float* bl = (const float*)d_in[9];
    float* out = (float*)d_out;

    const int* esrc = ei;
    const int* edst = ei + NE;

    char* ws = (char*)d_ws;
    size_t off = 0;
    auto alloc = [&](size_t bytes) {
        void* p = ws + off;
        off += (bytes + 255) & ~size_t(255);
        return p;
    };
    float* dinv   = (float*)alloc((size_t)NN * 4);
    int*   rowptr = (int*)alloc((size_t)(NN + 1) * 4);
    int*   HM     = (int*)alloc((size_t)NM * 4);        // 0.8 MB scan matrix
    int*   bsum   = (int*)alloc((size_t)(NMB + 1) * 4);
    int*   boff   = (int*)alloc((size_t)(NMB + 1) * 4);
    int*   ssrc   = (int*)alloc((size_t)NE * 4);        // 12.8 MB
    u16*   tbuf   = (u16*)alloc((size_t)NE * 4);        // 12.8 MB: part(int) overlay / U(bf16)
    u16*   agg    = (u16*)alloc((size_t)NN * HD * 2);   // 12.8 MB (h1/h2 bf16)
    float* sums   = (float*)alloc((size_t)NG * HD * 4);
    // part overlays tbuf: dead before gemm1 writes tbuf
    int* part = (int*)tbuf;

    // 1. contention-free radix partition -> ssrc (+ rowptr, dinv)
    k_blkhist<<<NPB, 256, 0, stream>>>(edst, HM, NE);
    k_scanA<<<NMB, 1024, 0, stream>>>(HM, bsum, NM);
    k_scan2<<<1, 256, 0, stream>>>(bsum, boff, NMB);
    k_scanC<<<(NM + 255) / 256, 256, 0, stream>>>(HM, boff, NM);
    k_place<<<NPB, 256, 0, stream>>>(esrc, edst, HM, part, NE);
    k_phaseB<<<NBUCK, 256, 0, stream>>>(part, HM, rowptr, ssrc, dinv, NE);

    // 2. layer 1: U1 = bf16((x@W1)*dinv) ; h1 = bf16(relu(...)) -> agg
    k_gemm<DIN, float><<<(NN + 63) / 64, 256, 0, stream>>>(x, W1, dinv, tbuf, NN);
    k_gather<<<2048, 256, 0, stream>>>(rowptr, ssrc, dinv, tbuf, b1, agg, NN);

    // 3. layer 2: U2 = bf16((h1@W2)*dinv) ; h2 -> agg (h1 dead after gemm2)
    k_gemm<HD, u16><<<(NN + 63) / 64, 256, 0, stream>>>(agg, W2, dinv, tbuf, NN);
    k_gather<<<2048, 256, 0, stream>>>(rowptr, ssrc, dinv, tbuf, b2, agg, NN);

    // 4. pool (segmented, conflict-free flushes) + head (binary-search counts)
    hipMemsetAsync(sums, 0, (size_t)NG * HD * 4, stream);
    k_pool<<<(NN + 255) / 256, 256, 0, stream>>>(agg, batch, sums, NN);
    k_final<<<NG, 64, 0, stream>>>(sums, batch, Wl, bl, out, NN);
}